// Round 2
// baseline (126177.771 us; speedup 1.0000x reference)
//
#include <hip/hip_runtime.h>

#define SS 16384
#define DD 1024
#define HH 1024
#define G4H 4096
#define SPINCAP (1<<22)

typedef unsigned long long u64;
typedef unsigned int u32;
typedef unsigned short ushort_t;

typedef __attribute__((ext_vector_type(8))) short bf16x8;
typedef __attribute__((ext_vector_type(4))) float f32x4;

__device__ __forceinline__ float sigm(float x){ return 1.0f/(1.0f+__expf(-x)); }
__device__ __forceinline__ float tanh_fast(float x){ return 1.0f - 2.0f/(__expf(2.0f*x)+1.0f); }

__device__ __forceinline__ ushort_t f2bf(float f){
    u32 u = __float_as_uint(f);
    u32 r = (u + 0x7FFFu + ((u>>16)&1u)) >> 16;
    return (ushort_t)r;
}

// any fp16 half == 0xFFFF (sentinel) -> not ready
__device__ __forceinline__ bool h_ok(u64 v){
    return (((v      )&0xFFFFull)!=0xFFFFull) &&
           (((v>>16)&0xFFFFull)!=0xFFFFull) &&
           (((v>>32)&0xFFFFull)!=0xFFFFull) &&
           (((v>>48)          )!=0xFFFFull);
}

// ---------------- prep: fp32 -> bf16 conversions + bias ----------------
__global__ __launch_bounds__(256) void prep_kernel(
    const float* __restrict__ x, const float* __restrict__ wih,
    const float* __restrict__ bih, const float* __restrict__ bhh,
    ushort_t* __restrict__ xb, ushort_t* __restrict__ wb, float* __restrict__ bias)
{
    long long i = (long long)blockIdx.x*256 + threadIdx.x;
    const long long NX = (long long)SS*DD;      // 16777216
    const long long NW = (long long)G4H*DD;     // 4194304
    if (i < NX) { xb[i] = f2bf(x[i]); }
    else if (i < NX+NW) { long long j=i-NX; wb[j]=f2bf(wih[j]); }
    else { int j=(int)(i-NX-NW); if (j < G4H) bias[j]=bih[j]+bhh[j]; }
}

// ---------------- GEMM: xg = x @ W_ih^T + bias, fp16 out ----------------
#define LDA 40  // padded LDS row stride (bf16 elems)

__global__ __launch_bounds__(256) void gemm_kernel(
    const ushort_t* __restrict__ A, const ushort_t* __restrict__ B,
    const float* __restrict__ bias, _Float16* __restrict__ Cg)
{
    __shared__ ushort_t At[128*LDA];
    __shared__ ushort_t Bt[128*LDA];
    const int tid  = threadIdx.x;
    const int lane = tid & 63;
    const int wv   = tid >> 6;
    const int wm   = wv >> 1, wn = wv & 1;
    const int m0   = blockIdx.y * 128;
    const int n0   = blockIdx.x * 128;
    const int quad = lane >> 4;
    const int l16  = lane & 15;

    f32x4 acc[4][4];
    #pragma unroll
    for (int a=0;a<4;a++)
      #pragma unroll
      for (int b=0;b<4;b++) acc[a][b] = (f32x4){0.f,0.f,0.f,0.f};

    for (int kb = 0; kb < DD; kb += 32) {
        #pragma unroll
        for (int s=0;s<2;s++){
            int ch  = tid*2+s;            // 0..511
            int row = ch >> 2;
            int ko  = (ch & 3) * 8;
            uint4 va = *(const uint4*)(A + (long long)(m0+row)*DD + kb + ko);
            *(uint4*)(At + row*LDA + ko) = va;
            uint4 vb = *(const uint4*)(B + (long long)(n0+row)*DD + kb + ko);
            *(uint4*)(Bt + row*LDA + ko) = vb;
        }
        __syncthreads();
        bf16x8 af[4], bfr[4];
        #pragma unroll
        for (int mi=0;mi<4;mi++){
            int r = wm*64 + mi*16 + l16;
            af[mi] = *(const bf16x8*)(At + r*LDA + quad*8);
        }
        #pragma unroll
        for (int ni=0;ni<4;ni++){
            int r = wn*64 + ni*16 + l16;
            bfr[ni] = *(const bf16x8*)(Bt + r*LDA + quad*8);
        }
        #pragma unroll
        for (int mi=0;mi<4;mi++)
          #pragma unroll
          for (int ni=0;ni<4;ni++)
            acc[mi][ni] = __builtin_amdgcn_mfma_f32_16x16x32_bf16(af[mi], bfr[ni], acc[mi][ni], 0,0,0);
        __syncthreads();
    }
    #pragma unroll
    for (int mi=0;mi<4;mi++){
      #pragma unroll
      for (int ni=0;ni<4;ni++){
        int col = n0 + wn*64 + ni*16 + l16;
        float bv = bias[col];
        #pragma unroll
        for (int r=0;r<4;r++){
            int rowg = m0 + wm*64 + mi*16 + quad*4 + r;
            Cg[(long long)rowg*G4H + col] = (_Float16)(acc[mi][ni][r] + bv);
        }
      }
    }
}

// ---------------- persistent LSTM scan: barrier-free, 1 unit per wave ----------------
__global__ __launch_bounds__(256, 1) void scan_kernel(
    const float* __restrict__ whh, const _Float16* __restrict__ xg,
    u64* __restrict__ pk64, ushort_t* __restrict__ pk16)
{
    const int tid  = threadIdx.x;
    const int lane = tid & 63;
    const int wv   = tid >> 6;
    const int u    = blockIdx.x*4 + wv;   // hidden unit owned by this wave

    // W_hh rows for all 4 gates of unit u; each lane holds cols 16*lane..16*lane+15
    float Wr[4][16];
    #pragma unroll
    for (int g=0; g<4; ++g){
        const float* rp = whh + (long long)(g*HH + u)*HH + 16*lane;
        #pragma unroll
        for (int q=0;q<4;q++){
            float4 v = *(const float4*)(rp + 4*q);
            Wr[g][4*q+0]=v.x; Wr[g][4*q+1]=v.y; Wr[g][4*q+2]=v.z; Wr[g][4*q+3]=v.w;
        }
    }

    float c_st = 0.0f;   // replicated in every lane (identical arithmetic)
    float xgv  = 0.0f;   // lanes 0..3: xg for gate 'lane' of unit u, step t
    if (lane < 4) xgv = (float)xg[(long long)lane*HH + u];

    for (int t=0; t<SS; ++t){
        float hv[16];
        if (t == 0){
            #pragma unroll
            for (int j=0;j<16;j++) hv[j]=0.f;
        } else {
            const u64* base = pk64 + (long long)(t-1)*256 + 4*lane;
            u64 r0, r1, r2, r3;
            // phase 1: cheap poll on one word while waiting for the burst
            r0 = __hip_atomic_load(base, __ATOMIC_RELAXED, __HIP_MEMORY_SCOPE_AGENT);
            int spin = 0;
            while (!h_ok(r0)){
                __builtin_amdgcn_s_sleep(1);
                r0 = __hip_atomic_load(base, __ATOMIC_RELAXED, __HIP_MEMORY_SCOPE_AGENT);
                if (++spin > SPINCAP) break;
            }
            // phase 2: the rest (usually already arrived)
            r1 = __hip_atomic_load(base+1, __ATOMIC_RELAXED, __HIP_MEMORY_SCOPE_AGENT);
            r2 = __hip_atomic_load(base+2, __ATOMIC_RELAXED, __HIP_MEMORY_SCOPE_AGENT);
            r3 = __hip_atomic_load(base+3, __ATOMIC_RELAXED, __HIP_MEMORY_SCOPE_AGENT);
            bool d1 = h_ok(r1), d2 = h_ok(r2), d3 = h_ok(r3);
            spin = 0;
            while (!(d1 && d2 && d3)){
                __builtin_amdgcn_s_sleep(1);
                if (!d1){ r1 = __hip_atomic_load(base+1, __ATOMIC_RELAXED, __HIP_MEMORY_SCOPE_AGENT); d1 = h_ok(r1); }
                if (!d2){ r2 = __hip_atomic_load(base+2, __ATOMIC_RELAXED, __HIP_MEMORY_SCOPE_AGENT); d2 = h_ok(r2); }
                if (!d3){ r3 = __hip_atomic_load(base+3, __ATOMIC_RELAXED, __HIP_MEMORY_SCOPE_AGENT); d3 = h_ok(r3); }
                if (++spin > SPINCAP) break;
            }
            union Uc { u64 u; _Float16 f[4]; } c0,c1,c2,c3;
            c0.u=r0; c1.u=r1; c2.u=r2; c3.u=r3;
            #pragma unroll
            for (int m=0;m<4;m++){
                hv[0+m]  = (float)c0.f[m];
                hv[4+m]  = (float)c1.f[m];
                hv[8+m]  = (float)c2.f[m];
                hv[12+m] = (float)c3.f[m];
            }
        }
        // prefetch next step's xg (overlaps the FMA/reduce/gate chain)
        float xgn = 0.f;
        if (lane < 4 && t+1 < SS)
            xgn = (float)xg[(long long)(t+1)*G4H + lane*HH + u];

        float s0=0.f, s1=0.f, s2=0.f, s3=0.f;
        if      (lane == 0) s0 = xgv;
        else if (lane == 1) s1 = xgv;
        else if (lane == 2) s2 = xgv;
        else if (lane == 3) s3 = xgv;
        #pragma unroll
        for (int j=0;j<16;j++){
            float h = hv[j];
            s0 += Wr[0][j]*h; s1 += Wr[1][j]*h;
            s2 += Wr[2][j]*h; s3 += Wr[3][j]*h;
        }
        #pragma unroll
        for (int off=32; off>=1; off>>=1){
            s0 += __shfl_xor(s0, off, 64);
            s1 += __shfl_xor(s1, off, 64);
            s2 += __shfl_xor(s2, off, 64);
            s3 += __shfl_xor(s3, off, 64);
        }
        // all lanes compute gates redundantly (keeps c replicated, no broadcast)
        c_st = sigm(s1)*c_st + sigm(s0)*tanh_fast(s2);
        float hval = sigm(s3)*tanh_fast(c_st);
        if (lane == 0){
            _Float16 hf = (_Float16)hval;
            ushort_t hb;
            __builtin_memcpy(&hb, &hf, 2);
            __hip_atomic_store(pk16 + (long long)t*HH + u, hb,
                               __ATOMIC_RELAXED, __HIP_MEMORY_SCOPE_AGENT);
        }
        xgv = xgn;
    }
}

// ---------------- alpha = sigmoid(hs @ W_fc^T + b_fc) ----------------
__global__ __launch_bounds__(256) void alpha_kernel(
    const u64* __restrict__ packed, const float* __restrict__ wfc,
    const float* __restrict__ bfc, float* __restrict__ alpha)
{
    int row  = blockIdx.x*4 + (threadIdx.x>>6);
    int lane = threadIdx.x & 63;
    const u64* p = packed + (long long)row*256 + 4*lane;
    float s = 0.f;
    #pragma unroll
    for (int q=0;q<4;q++){
        union { u64 u; _Float16 h[4]; } cv; cv.u = p[q];
        float4 wvv = *(const float4*)(wfc + 16*lane + 4*q);
        s += (float)cv.h[0]*wvv.x + (float)cv.h[1]*wvv.y
           + (float)cv.h[2]*wvv.z + (float)cv.h[3]*wvv.w;
    }
    #pragma unroll
    for (int off=32; off>=1; off>>=1) s += __shfl_xor(s, off, 64);
    if (lane==0) alpha[row] = sigm(s + bfc[0]);
}

// ---------------- finalize: affine scans + loss ----------------
__global__ __launch_bounds__(256) void finalize_kernel(
    const float* __restrict__ uttr_pred, const float* __restrict__ timing_label,
    const float* __restrict__ alpha, float* __restrict__ out)
{
    const int n = SS-1;  // 16383
    const int tid = threadIdx.x;
    __shared__ float Ms[256], Cs[256], Pre[256];
    __shared__ int Fi[256];
    float* out_y = out + 1;
    float* out_a = out + 1 + n;
    float* out_u = out + 1 + 2*n;

    int i0 = tid*64;
    int i1 = i0+64; if (i1 > n) i1 = n;

    float M = 1.f, C = 0.f;
    int fi = 0x7fffffff;
    for (int i=i0; i<i1; ++i){
        float u = 1.f - uttr_pred[i+1];
        float a = alpha[i+1];
        out_u[i] = u;
        M = u*M;
        C = u*C + (1.f-u)*a;
        if (timing_label[i] > 0.8f && i < fi) fi = i;
    }
    Ms[tid]=M; Cs[tid]=C; Fi[tid]=fi;
    __syncthreads();
    if (tid==0){
        float x=0.f;
        for (int tt=0; tt<256; ++tt){ Pre[tt]=x; x = Ms[tt]*x + Cs[tt]; }
        int best=0x7fffffff;
        for (int tt=0; tt<256; ++tt) best = min(best, Fi[tt]);
        Fi[0]=best;
    }
    __syncthreads();
    float x = Pre[tid];
    float My=1.f, Cy=0.f;
    for (int i=i0;i<i1;++i){
        float u = 1.f - uttr_pred[i+1];
        float a = alpha[i+1];
        x = u*x + (1.f-u)*a;
        out_a[i] = x;
        float Af = 1.f - x;
        float Bf = x*u;
        My = Af*My;
        Cy = Af*Cy + Bf;
    }
    Ms[tid]=My; Cs[tid]=Cy;
    __syncthreads();
    if (tid==0){
        float y=0.f;
        for (int tt=0;tt<256;++tt){ Pre[tt]=y; y = Ms[tt]*y + Cs[tt]; }
    }
    __syncthreads();
    float y = Pre[tid];
    for (int i=i0;i<i1;++i){
        float ag = out_a[i];
        float u  = out_u[i];
        y = ag*u + (1.f-ag)*y;
        out_y[i] = y;
    }
    __syncthreads();
    if (tid==0){
        int best = Fi[0];
        bool exists = (best != 0x7fffffff);
        int idx = exists ? best : 0;
        float u_at = 1.f - uttr_pred[idx+1];
        float y_at = out_y[idx];
        float y_last = out_y[n-1];
        float loss;
        if (exists) loss = (u_at < 0.5f) ? 0.f : (y_at-0.8f)*(y_at-0.8f);
        else        loss = (y_last >= 0.8f) ? (y_last-0.4f)*(y_last-0.4f) : 0.f;
        out[0] = loss;
    }
}

// ---------------- launch ----------------
extern "C" void kernel_launch(void* const* d_in, const int* in_sizes, int n_in,
                              void* d_out, int out_size, void* d_ws, size_t ws_size,
                              hipStream_t stream)
{
    const float* x    = (const float*)d_in[0];
    const float* up   = (const float*)d_in[1];
    const float* tl   = (const float*)d_in[2];
    const float* wih  = (const float*)d_in[4];
    const float* whh  = (const float*)d_in[5];
    const float* bih  = (const float*)d_in[6];
    const float* bhh  = (const float*)d_in[7];
    const float* wfc  = (const float*)d_in[8];
    const float* bfc  = (const float*)d_in[9];
    float* out = (float*)d_out;

    char* ws = (char*)d_ws;
    ushort_t* xb   = (ushort_t*)(ws);                      // 32 MB  x bf16
    ushort_t* wb   = (ushort_t*)(ws + 33554432);           //  8 MB  W_ih bf16
    _Float16* xg   = (_Float16*)(ws + 41943040);           // 128 MB xg fp16
    u64*      pkd  = (u64*)     (ws + 176160768);          // 32 MB  packed h history
    float*    alp  = (float*)   (ws + 209715200);          // 64 KB  alpha
    float*    bias = (float*)   (ws + 209780736);          // 16 KB  bias

    hipMemsetAsync(pkd, 0xFF, (size_t)SS*HH*2, stream);    // sentinel init
    prep_kernel<<<81936, 256, 0, stream>>>(x, wih, bih, bhh, xb, wb, bias);
    gemm_kernel<<<dim3(G4H/128, SS/128), 256, 0, stream>>>(xb, wb, bias, xg);
    scan_kernel<<<256, 256, 0, stream>>>(whh, xg, pkd, (ushort_t*)pkd);
    alpha_kernel<<<SS/4, 256, 0, stream>>>(pkd, wfc, bfc, alp);
    finalize_kernel<<<1, 256, 0, stream>>>(up, tl, alp, out);
}

// Round 3
// 61934.235 us; speedup vs baseline: 2.0373x; 2.0373x over previous
//
#include <hip/hip_runtime.h>

#define SS 16384
#define DD 1024
#define HH 1024
#define G4H 4096
#define SPINCAP (1<<22)

typedef unsigned long long u64;
typedef unsigned int u32;
typedef unsigned short ushort_t;

typedef __attribute__((ext_vector_type(8))) short bf16x8;
typedef __attribute__((ext_vector_type(4))) float f32x4;
typedef __attribute__((ext_vector_type(2))) _Float16 half2_t;

__device__ __forceinline__ float sigm(float x){ return 1.0f/(1.0f+__expf(-x)); }
__device__ __forceinline__ float tanh_fast(float x){ return 1.0f - 2.0f/(__expf(2.0f*x)+1.0f); }

__device__ __forceinline__ ushort_t f2bf(float f){
    u32 u = __float_as_uint(f);
    u32 r = (u + 0x7FFFu + ((u>>16)&1u)) >> 16;
    return (ushort_t)r;
}

#if __has_builtin(__builtin_amdgcn_fdot2)
__device__ __forceinline__ float FDOT2(half2_t a, half2_t b, float c){
    return __builtin_amdgcn_fdot2(a, b, c, false);
}
#else
__device__ __forceinline__ float FDOT2(half2_t a, half2_t b, float c){
    return c + (float)a.x*(float)b.x + (float)a.y*(float)b.y;
}
#endif

// word ready iff low fp16 half != 0xFFFF (whole u64 is stored atomically)
__device__ __forceinline__ bool ok16(u64 v){ return (v & 0xFFFFull) != 0xFFFFull; }

// ---------------- prep: fp32 -> bf16 conversions + bias ----------------
__global__ __launch_bounds__(256) void prep_kernel(
    const float* __restrict__ x, const float* __restrict__ wih,
    const float* __restrict__ bih, const float* __restrict__ bhh,
    ushort_t* __restrict__ xb, ushort_t* __restrict__ wb, float* __restrict__ bias)
{
    long long i = (long long)blockIdx.x*256 + threadIdx.x;
    const long long NX = (long long)SS*DD;      // 16777216
    const long long NW = (long long)G4H*DD;     // 4194304
    if (i < NX) { xb[i] = f2bf(x[i]); }
    else if (i < NX+NW) { long long j=i-NX; wb[j]=f2bf(wih[j]); }
    else { int j=(int)(i-NX-NW); if (j < G4H) bias[j]=bih[j]+bhh[j]; }
}

// ---------------- GEMM: xg = x @ W_ih^T + bias, fp16 out ----------------
#define LDA 40  // padded LDS row stride (bf16 elems)

__global__ __launch_bounds__(256) void gemm_kernel(
    const ushort_t* __restrict__ A, const ushort_t* __restrict__ B,
    const float* __restrict__ bias, _Float16* __restrict__ Cg)
{
    __shared__ ushort_t At[128*LDA];
    __shared__ ushort_t Bt[128*LDA];
    const int tid  = threadIdx.x;
    const int lane = tid & 63;
    const int wv   = tid >> 6;
    const int wm   = wv >> 1, wn = wv & 1;
    const int m0   = blockIdx.y * 128;
    const int n0   = blockIdx.x * 128;
    const int quad = lane >> 4;
    const int l16  = lane & 15;

    f32x4 acc[4][4];
    #pragma unroll
    for (int a=0;a<4;a++)
      #pragma unroll
      for (int b=0;b<4;b++) acc[a][b] = (f32x4){0.f,0.f,0.f,0.f};

    for (int kb = 0; kb < DD; kb += 32) {
        #pragma unroll
        for (int s=0;s<2;s++){
            int ch  = tid*2+s;            // 0..511
            int row = ch >> 2;
            int ko  = (ch & 3) * 8;
            uint4 va = *(const uint4*)(A + (long long)(m0+row)*DD + kb + ko);
            *(uint4*)(At + row*LDA + ko) = va;
            uint4 vb = *(const uint4*)(B + (long long)(n0+row)*DD + kb + ko);
            *(uint4*)(Bt + row*LDA + ko) = vb;
        }
        __syncthreads();
        bf16x8 af[4], bfr[4];
        #pragma unroll
        for (int mi=0;mi<4;mi++){
            int r = wm*64 + mi*16 + l16;
            af[mi] = *(const bf16x8*)(At + r*LDA + quad*8);
        }
        #pragma unroll
        for (int ni=0;ni<4;ni++){
            int r = wn*64 + ni*16 + l16;
            bfr[ni] = *(const bf16x8*)(Bt + r*LDA + quad*8);
        }
        #pragma unroll
        for (int mi=0;mi<4;mi++)
          #pragma unroll
          for (int ni=0;ni<4;ni++)
            acc[mi][ni] = __builtin_amdgcn_mfma_f32_16x16x32_bf16(af[mi], bfr[ni], acc[mi][ni], 0,0,0);
        __syncthreads();
    }
    #pragma unroll
    for (int mi=0;mi<4;mi++){
      #pragma unroll
      for (int ni=0;ni<4;ni++){
        int col = n0 + wn*64 + ni*16 + l16;
        float bv = bias[col];
        #pragma unroll
        for (int r=0;r<4;r++){
            int rowg = m0 + wm*64 + mi*16 + quad*4 + r;
            Cg[(long long)rowg*G4H + col] = (_Float16)(acc[mi][ni][r] + bv);
        }
      }
    }
}

// ---------------- persistent LSTM scan: 1 wave per WG, 4 units per wave ----------------
// Rows r = g*4+u (gate-major). Lane L covers h-cols 16L..16L+15.
__global__ __launch_bounds__(64, 1) void scan_kernel(
    const float* __restrict__ whh, const _Float16* __restrict__ xg,
    u64* __restrict__ pkd)
{
    const int lane = threadIdx.x;        // 0..63
    const int w    = blockIdx.x;         // units 4w..4w+3

    // weights -> packed fp16 pairs in registers (128 VGPRs)
    half2_t Wp[16][8];
    #pragma unroll
    for (int g=0; g<4; ++g){
        #pragma unroll
        for (int u=0; u<4; ++u){
            const float* rp = whh + (long long)(g*HH + 4*w + u)*HH + 16*lane;
            int r = g*4 + u;
            #pragma unroll
            for (int p=0;p<8;p++){
                float2 f = *(const float2*)(rp + 2*p);
                half2_t hh; hh.x = (_Float16)f.x; hh.y = (_Float16)f.y;
                Wp[r][p] = hh;
            }
        }
    }

    float c0=0.f, c1=0.f, c2=0.f, c3=0.f;   // replicated in every lane
    // xg prefetch for t=0: lane g<4 holds 4 fp16 (units 4w..4w+3) of gate g
    u64 xgv = 0;
    if (lane < 4) xgv = *(const u64*)(xg + (long long)lane*HH + 4*w);

    for (int t=0; t<SS; ++t){
        u64 r0=0, r1=0, r2=0, r3=0;
        if (t > 0){
            const u64* base = pkd + (long long)(t-1)*256 + 4*lane;
            bool d0=false,d1=false,d2=false,d3=false;
            int spin = 0;
            do {
                if(!d0) r0 = __hip_atomic_load(base+0, __ATOMIC_RELAXED, __HIP_MEMORY_SCOPE_AGENT);
                if(!d1) r1 = __hip_atomic_load(base+1, __ATOMIC_RELAXED, __HIP_MEMORY_SCOPE_AGENT);
                if(!d2) r2 = __hip_atomic_load(base+2, __ATOMIC_RELAXED, __HIP_MEMORY_SCOPE_AGENT);
                if(!d3) r3 = __hip_atomic_load(base+3, __ATOMIC_RELAXED, __HIP_MEMORY_SCOPE_AGENT);
                d0 = ok16(r0); d1 = ok16(r1); d2 = ok16(r2); d3 = ok16(r3);
            } while (!(d0&&d1&&d2&&d3) && ++spin < SPINCAP);
        }
        // prefetch next step's xg (overlaps dot/reduce)
        u64 xgn = 0;
        if (lane < 4 && t+1 < SS)
            xgn = *(const u64*)(xg + (long long)(t+1)*G4H + lane*HH + 4*w);

        // accumulators: 16 gate-row partials
        float acc[16];
        #pragma unroll
        for (int r=0;r<16;r++) acc[r]=0.f;
        // inject xg on lanes 0..3 (gate = lane)
        if (lane < 4){
            union { u64 u; _Float16 f[4]; } xv; xv.u = xgv;
            #pragma unroll
            for (int u_=0; u_<4; ++u_) acc[lane*4 + u_] += (float)xv.f[u_];
        }
        // packed h for this lane's 16 columns
        union { u64 u[4]; half2_t h[8]; } hp;
        hp.u[0]=r0; hp.u[1]=r1; hp.u[2]=r2; hp.u[3]=r3;
        #pragma unroll
        for (int r=0;r<16;r++){
            #pragma unroll
            for (int p=0;p<8;p++)
                acc[r] = FDOT2(Wp[r][p], hp.h[p], acc[r]);
        }
        // butterfly: every lane ends with all 16 full sums
        #pragma unroll
        for (int off=32; off>=1; off>>=1){
            #pragma unroll
            for (int r=0;r<16;r++)
                acc[r] += __shfl_xor(acc[r], off, 64);
        }
        // gates, all lanes redundant (no gathers)
        c0 = sigm(acc[4+0])*c0 + sigm(acc[0])*tanh_fast(acc[8+0]);
        c1 = sigm(acc[4+1])*c1 + sigm(acc[1])*tanh_fast(acc[8+1]);
        c2 = sigm(acc[4+2])*c2 + sigm(acc[2])*tanh_fast(acc[8+2]);
        c3 = sigm(acc[4+3])*c3 + sigm(acc[3])*tanh_fast(acc[8+3]);
        float h0 = sigm(acc[12+0])*tanh_fast(c0);
        float h1 = sigm(acc[12+1])*tanh_fast(c1);
        float h2 = sigm(acc[12+2])*tanh_fast(c2);
        float h3 = sigm(acc[12+3])*tanh_fast(c3);
        if (lane == 0){
            union { u64 u; _Float16 f[4]; } pk;
            pk.f[0]=(_Float16)h0; pk.f[1]=(_Float16)h1;
            pk.f[2]=(_Float16)h2; pk.f[3]=(_Float16)h3;
            __hip_atomic_store(&pkd[(long long)t*256 + w], pk.u,
                               __ATOMIC_RELAXED, __HIP_MEMORY_SCOPE_AGENT);
        }
        xgv = xgn;
    }
}

// ---------------- alpha = sigmoid(hs @ W_fc^T + b_fc) ----------------
__global__ __launch_bounds__(256) void alpha_kernel(
    const u64* __restrict__ packed, const float* __restrict__ wfc,
    const float* __restrict__ bfc, float* __restrict__ alpha)
{
    int row  = blockIdx.x*4 + (threadIdx.x>>6);
    int lane = threadIdx.x & 63;
    const u64* p = packed + (long long)row*256 + 4*lane;
    float s = 0.f;
    #pragma unroll
    for (int q=0;q<4;q++){
        union { u64 u; _Float16 h[4]; } cv; cv.u = p[q];
        float4 wvv = *(const float4*)(wfc + 16*lane + 4*q);
        s += (float)cv.h[0]*wvv.x + (float)cv.h[1]*wvv.y
           + (float)cv.h[2]*wvv.z + (float)cv.h[3]*wvv.w;
    }
    #pragma unroll
    for (int off=32; off>=1; off>>=1) s += __shfl_xor(s, off, 64);
    if (lane==0) alpha[row] = sigm(s + bfc[0]);
}

// ---------------- finalize: affine scans + loss ----------------
__global__ __launch_bounds__(256) void finalize_kernel(
    const float* __restrict__ uttr_pred, const float* __restrict__ timing_label,
    const float* __restrict__ alpha, float* __restrict__ out)
{
    const int n = SS-1;  // 16383
    const int tid = threadIdx.x;
    __shared__ float Ms[256], Cs[256], Pre[256];
    __shared__ int Fi[256];
    float* out_y = out + 1;
    float* out_a = out + 1 + n;
    float* out_u = out + 1 + 2*n;

    int i0 = tid*64;
    int i1 = i0+64; if (i1 > n) i1 = n;

    float M = 1.f, C = 0.f;
    int fi = 0x7fffffff;
    for (int i=i0; i<i1; ++i){
        float u = 1.f - uttr_pred[i+1];
        float a = alpha[i+1];
        out_u[i] = u;
        M = u*M;
        C = u*C + (1.f-u)*a;
        if (timing_label[i] > 0.8f && i < fi) fi = i;
    }
    Ms[tid]=M; Cs[tid]=C; Fi[tid]=fi;
    __syncthreads();
    if (tid==0){
        float x=0.f;
        for (int tt=0; tt<256; ++tt){ Pre[tt]=x; x = Ms[tt]*x + Cs[tt]; }
        int best=0x7fffffff;
        for (int tt=0; tt<256; ++tt) best = min(best, Fi[tt]);
        Fi[0]=best;
    }
    __syncthreads();
    float x = Pre[tid];
    float My=1.f, Cy=0.f;
    for (int i=i0;i<i1;++i){
        float u = 1.f - uttr_pred[i+1];
        float a = alpha[i+1];
        x = u*x + (1.f-u)*a;
        out_a[i] = x;
        float Af = 1.f - x;
        float Bf = x*u;
        My = Af*My;
        Cy = Af*Cy + Bf;
    }
    Ms[tid]=My; Cs[tid]=Cy;
    __syncthreads();
    if (tid==0){
        float y=0.f;
        for (int tt=0;tt<256;++tt){ Pre[tt]=y; y = Ms[tt]*y + Cs[tt]; }
    }
    __syncthreads();
    float y = Pre[tid];
    for (int i=i0;i<i1;++i){
        float ag = out_a[i];
        float u  = out_u[i];
        y = ag*u + (1.f-ag)*y;
        out_y[i] = y;
    }
    __syncthreads();
    if (tid==0){
        int best = Fi[0];
        bool exists = (best != 0x7fffffff);
        int idx = exists ? best : 0;
        float u_at = 1.f - uttr_pred[idx+1];
        float y_at = out_y[idx];
        float y_last = out_y[n-1];
        float loss;
        if (exists) loss = (u_at < 0.5f) ? 0.f : (y_at-0.8f)*(y_at-0.8f);
        else        loss = (y_last >= 0.8f) ? (y_last-0.4f)*(y_last-0.4f) : 0.f;
        out[0] = loss;
    }
}

// ---------------- launch ----------------
extern "C" void kernel_launch(void* const* d_in, const int* in_sizes, int n_in,
                              void* d_out, int out_size, void* d_ws, size_t ws_size,
                              hipStream_t stream)
{
    const float* x    = (const float*)d_in[0];
    const float* up   = (const float*)d_in[1];
    const float* tl   = (const float*)d_in[2];
    const float* wih  = (const float*)d_in[4];
    const float* whh  = (const float*)d_in[5];
    const float* bih  = (const float*)d_in[6];
    const float* bhh  = (const float*)d_in[7];
    const float* wfc  = (const float*)d_in[8];
    const float* bfc  = (const float*)d_in[9];
    float* out = (float*)d_out;

    char* ws = (char*)d_ws;
    ushort_t* xb   = (ushort_t*)(ws);                      // 32 MB  x bf16
    ushort_t* wb   = (ushort_t*)(ws + 33554432);           //  8 MB  W_ih bf16
    _Float16* xg   = (_Float16*)(ws + 41943040);           // 128 MB xg fp16
    u64*      pkd  = (u64*)     (ws + 176160768);          // 32 MB  packed h history
    float*    alp  = (float*)   (ws + 209715200);          // 64 KB  alpha
    float*    bias = (float*)   (ws + 209780736);          // 16 KB  bias

    hipMemsetAsync(pkd, 0xFF, (size_t)SS*HH*2, stream);    // sentinel init
    prep_kernel<<<81936, 256, 0, stream>>>(x, wih, bih, bhh, xb, wb, bias);
    gemm_kernel<<<dim3(G4H/128, SS/128), 256, 0, stream>>>(xb, wb, bias, xg);
    scan_kernel<<<256, 64, 0, stream>>>(whh, xg, pkd);
    alpha_kernel<<<SS/4, 256, 0, stream>>>(pkd, wfc, bfc, alp);
    finalize_kernel<<<1, 256, 0, stream>>>(up, tl, alp, out);
}